// Round 1
// baseline (1787.667 us; speedup 1.0000x reference)
//
#include <hip/hip_runtime.h>

// RNN_SingleOutput: 2-layer Elman ReLU RNN, B=256 T=512 I=64 H=256, fp32.
// Plan:
//  K1: per-batch persistent block, fused input-proj + L0 recurrence.
//      W_ih0/W_hh0 row-halves in VGPRs; h_prev broadcast from LDS. -> h1 (ws)
//  K2: pre1 = h1 @ W_ih1^T + b_ih1 + b_hh1, same register-row + LDS-broadcast
//      pattern, in-place over ws (row-wise, safe per block).
//  K3: L1 recurrence from staged pre1 + fused FC head -> out.
// ws requirement: B*T*H*4 = 128 MiB.

#define B_ 256
#define T_ 512
#define I_ 64
#define H_ 256

__global__ __launch_bounds__(512, 2) void k_layer0(
    const float* __restrict__ x, const float* __restrict__ Wih,
    const float* __restrict__ Whh, const float* __restrict__ bih,
    const float* __restrict__ bhh, float* __restrict__ h1out)
{
    const int b   = blockIdx.x;
    const int tid = threadIdx.x;
    const int h   = tid & (H_ - 1);
    const int q   = tid >> 8;            // K-half: 0 or 1

    // Weight fragments in registers: W_ih0[h, 32q:32q+32], W_hh0[h, 128q:128q+128]
    float4 wih4[8];
    float4 whh4[32];
    {
        const float4* p = (const float4*)(Wih + (size_t)h * I_ + 32 * q);
#pragma unroll
        for (int i = 0; i < 8; ++i) wih4[i] = p[i];
        const float4* p2 = (const float4*)(Whh + (size_t)h * H_ + 128 * q);
#pragma unroll
        for (int i = 0; i < 32; ++i) whh4[i] = p2[i];
    }
    const float bias = bih[h] + bhh[h];

    __shared__ float4 xs4[(32 * I_) / 4];   // 32-step x chunk, 8 KB
    __shared__ float4 hprev4[H_ / 4];       // hidden state, 1 KB
    __shared__ float  partial[2][H_];       // split-K partials, 2 KB

    if (tid < H_ / 4) hprev4[tid] = make_float4(0.f, 0.f, 0.f, 0.f);
    __syncthreads();

    for (int t0 = 0; t0 < T_; t0 += 32) {
        // stage x[b, t0:t0+32, :] (contiguous 8 KB), coalesced
        ((float4*)xs4)[tid] =
            ((const float4*)(x + ((size_t)b * T_ + t0) * I_))[tid];
        __syncthreads();
#pragma unroll 1
        for (int tt = 0; tt < 32; ++tt) {
            float4 acc = make_float4(0.f, 0.f, 0.f, 0.f);
            const float4* hp = hprev4 + 32 * q;          // broadcast reads
#pragma unroll
            for (int i = 0; i < 32; ++i) {
                float4 hv = hp[i], w = whh4[i];
                acc.x += hv.x * w.x; acc.y += hv.y * w.y;
                acc.z += hv.z * w.z; acc.w += hv.w * w.w;
            }
            const float4* xp = xs4 + tt * (I_ / 4) + 8 * q;
#pragma unroll
            for (int i = 0; i < 8; ++i) {
                float4 xv = xp[i], w = wih4[i];
                acc.x += xv.x * w.x; acc.y += xv.y * w.y;
                acc.z += xv.z * w.z; acc.w += xv.w * w.w;
            }
            partial[q][h] = (acc.x + acc.y) + (acc.z + acc.w);
            __syncthreads();                              // B1
            if (tid < H_) {
                float v = partial[0][h] + partial[1][h] + bias;
                v = fmaxf(v, 0.f);
                ((float*)hprev4)[h] = v;                  // safe after B1
                h1out[((size_t)b * T_ + t0 + tt) * H_ + h] = v;
            }
            __syncthreads();                              // B2
        }
    }
}

// pre1 = h1 @ W_ih1^T + (b_ih1 + b_hh1), in place over `buf`.
__global__ __launch_bounds__(512, 2) void k_inproj1(
    float* __restrict__ buf, const float* __restrict__ Wih,
    const float* __restrict__ bih, const float* __restrict__ bhh)
{
    const int tid = threadIdx.x;
    const int h = tid & (H_ - 1), q = tid >> 8;

    float4 w4[32];                       // W_ih1[h, 128q:128q+128]
    const float4* p = (const float4*)(Wih + (size_t)h * H_ + 128 * q);
#pragma unroll
    for (int i = 0; i < 32; ++i) w4[i] = p[i];
    const float bias = bih[h] + bhh[h];

    __shared__ float4 rows4[(16 * H_) / 4];  // 16-row chunk, 16 KB
    __shared__ float  partial[2][H_];

    const size_t m0 = (size_t)blockIdx.x * 64;   // 64 rows per block
    for (int c = 0; c < 4; ++c) {
        const float* src = buf + (m0 + (size_t)c * 16) * H_;
        ((float4*)rows4)[tid]       = ((const float4*)src)[tid];
        ((float4*)rows4)[tid + 512] = ((const float4*)src)[tid + 512];
        __syncthreads();
#pragma unroll 1
        for (int r = 0; r < 16; ++r) {
            float4 acc = make_float4(0.f, 0.f, 0.f, 0.f);
            const float4* hp = rows4 + r * (H_ / 4) + 32 * q;
#pragma unroll
            for (int i = 0; i < 32; ++i) {
                float4 hv = hp[i], w = w4[i];
                acc.x += hv.x * w.x; acc.y += hv.y * w.y;
                acc.z += hv.z * w.z; acc.w += hv.w * w.w;
            }
            partial[q][h] = (acc.x + acc.y) + (acc.z + acc.w);
            __syncthreads();
            if (tid < H_)
                buf[(m0 + (size_t)c * 16 + r) * H_ + h] =
                    partial[0][h] + partial[1][h] + bias;
            __syncthreads();
        }
    }
}

__global__ __launch_bounds__(512, 2) void k_layer1(
    const float* __restrict__ pre1, const float* __restrict__ Whh,
    const float* __restrict__ Wfc, const float* __restrict__ bfcp,
    float* __restrict__ out)
{
    const int b = blockIdx.x, tid = threadIdx.x;
    const int h = tid & (H_ - 1), q = tid >> 8;

    float4 w4[32];                        // W_hh1[h, 128q:128q+128]
    const float4* p = (const float4*)(Whh + (size_t)h * H_ + 128 * q);
#pragma unroll
    for (int i = 0; i < 32; ++i) w4[i] = p[i];
    const float wfc = Wfc[h];
    const float bfc = bfcp[0];

    __shared__ float4 ps4[(16 * H_) / 4];  // 16-step pre1 chunk, 16 KB
    __shared__ float4 hprev4[H_ / 4];
    __shared__ float  partial[2][H_];
    __shared__ float  wavesum[4];

    if (tid < H_ / 4) hprev4[tid] = make_float4(0.f, 0.f, 0.f, 0.f);
    __syncthreads();

    for (int t0 = 0; t0 < T_; t0 += 16) {
        const float* src = pre1 + ((size_t)b * T_ + t0) * H_;
        ((float4*)ps4)[tid]       = ((const float4*)src)[tid];
        ((float4*)ps4)[tid + 512] = ((const float4*)src)[tid + 512];
        __syncthreads();
#pragma unroll 1
        for (int tt = 0; tt < 16; ++tt) {
            const int t = t0 + tt;
            // deferred FC store for step t-1 (wavesum stable: written between
            // B1/B2 of the previous step, next write only after this B1)
            if (tid == 0 && t > 0)
                out[(size_t)b * T_ + (t - 1)] =
                    wavesum[0] + wavesum[1] + wavesum[2] + wavesum[3] + bfc;

            float4 acc = make_float4(0.f, 0.f, 0.f, 0.f);
            const float4* hp = hprev4 + 32 * q;
#pragma unroll
            for (int i = 0; i < 32; ++i) {
                float4 hv = hp[i], w = w4[i];
                acc.x += hv.x * w.x; acc.y += hv.y * w.y;
                acc.z += hv.z * w.z; acc.w += hv.w * w.w;
            }
            partial[q][h] = (acc.x + acc.y) + (acc.z + acc.w);
            __syncthreads();                              // B1
            if (tid < H_) {
                float v = partial[0][h] + partial[1][h]
                        + ((const float*)ps4)[tt * H_ + h];
                v = fmaxf(v, 0.f);
                ((float*)hprev4)[h] = v;
                float fc = v * wfc;                       // FC head partial
#pragma unroll
                for (int off = 32; off > 0; off >>= 1)
                    fc += __shfl_down(fc, off, 64);
                if ((tid & 63) == 0) wavesum[tid >> 6] = fc;
            }
            __syncthreads();                              // B2
        }
    }
    if (tid == 0)
        out[(size_t)b * T_ + (T_ - 1)] =
            wavesum[0] + wavesum[1] + wavesum[2] + wavesum[3] + bfc;
}

extern "C" void kernel_launch(void* const* d_in, const int* in_sizes, int n_in,
                              void* d_out, int out_size, void* d_ws, size_t ws_size,
                              hipStream_t stream) {
    (void)in_sizes; (void)n_in; (void)out_size; (void)ws_size;
    const float* x    = (const float*)d_in[0];
    const float* Wih0 = (const float*)d_in[1];
    const float* Whh0 = (const float*)d_in[2];
    const float* bih0 = (const float*)d_in[3];
    const float* bhh0 = (const float*)d_in[4];
    const float* Wih1 = (const float*)d_in[5];
    const float* Whh1 = (const float*)d_in[6];
    const float* bih1 = (const float*)d_in[7];
    const float* bhh1 = (const float*)d_in[8];
    const float* Wfc  = (const float*)d_in[9];
    const float* bfc  = (const float*)d_in[10];

    float* buf = (float*)d_ws;      // needs B*T*H*4 = 128 MiB scratch
    float* out = (float*)d_out;

    k_layer0 <<<dim3(B_),            dim3(512), 0, stream>>>(x, Wih0, Whh0, bih0, bhh0, buf);
    k_inproj1<<<dim3((B_ * T_) / 64), dim3(512), 0, stream>>>(buf, Wih1, bih1, bhh1);
    k_layer1 <<<dim3(B_),            dim3(512), 0, stream>>>(buf, Whh1, Wfc, bfc, out);
}